// Round 1
// baseline (880.851 us; speedup 1.0000x reference)
//
#include <hip/hip_runtime.h>

// ---------------------------------------------------------------------------
// GCN: 3-layer, N=50000 nodes (128 feats), E=1.6M edges, 64 graphs.
//
// Algebra: segsum((h@W)[src]*w, tgt) == segsum(h[src]*w, tgt) @ W
//  => layers 2 and 3 share ONE aggregation pass A = segsum(h1[src]*w, tgt):
//     embed = A@W2 + b2
//     graph_embed[g] = (sum_{i in g} A[i]) @ W3 + n_g * b3
// Pipeline:
//   h_pre = x @ W1                      (GEMM K=128)
//   agg1  = scatter(h_pre)              (edge pass 1)
//   h1    = relu(agg1 + b1)
//   A     = scatter(h1)                 (edge pass 2)
//   embed = A @ W2 + b2  -> d_out[0:N*64]
//   B[g]  = sum_{i in g} A[i], counts[g]
//   g_emb = B @ W3 + counts*b3 -> d_out[N*64:]
// ---------------------------------------------------------------------------

#define THREADS 256

// C[M,64] = A[M,K] @ W[K,64] (+ bias). One block = 4 rows, lane = col.
template <int K, bool BIAS>
__global__ __launch_bounds__(THREADS) void gemm64(
    const float* __restrict__ A, const float* __restrict__ W,
    const float* __restrict__ bias, float* __restrict__ C, int M) {
  __shared__ float Ws[K * 64];   // [k][c] layout: lane c -> bank c%32, 2-way (free)
  __shared__ float xs[4][K];
  int tid = threadIdx.x;
  for (int i = tid; i < K * 64; i += THREADS) Ws[i] = W[i];
  int r0 = blockIdx.x * 4;
  for (int i = tid; i < 4 * K; i += THREADS) {
    int rl = i / K, k = i - rl * K;
    int r = r0 + rl;
    xs[rl][k] = (r < M) ? A[(size_t)r * K + k] : 0.f;
  }
  __syncthreads();
  int c = tid & 63;
  int rl = tid >> 6;
  int r = r0 + rl;
  if (r >= M) return;
  float acc = 0.f;
#pragma unroll
  for (int k = 0; k < K; ++k) acc += xs[rl][k] * Ws[k * 64 + c];
  if (BIAS) acc += bias[c];
  C[(size_t)r * 64 + c] = acc;
}

// One wave per contiguous edge chunk; lane = feature dim (64 dims == 64 lanes).
__global__ __launch_bounds__(THREADS) void scatter_edges(
    const float* __restrict__ h, const int* __restrict__ src,
    const int* __restrict__ tgt, const float* __restrict__ ew,
    float* __restrict__ agg, int E, int nwaves) {
  int lane = threadIdx.x & 63;
  int wid = blockIdx.x * (THREADS >> 6) + (threadIdx.x >> 6);
  int per = (E + nwaves - 1) / nwaves;
  int e0 = wid * per;
  int e1 = min(e0 + per, E);
  for (int e = e0; e < e1; ++e) {
    int s = src[e];
    int t = tgt[e];
    float w = ew[e];
    float v = h[(size_t)s * 64 + lane] * w;
    unsafeAtomicAdd(&agg[(size_t)t * 64 + lane], v);
  }
}

// out = relu(in + b), rows of width 64, vectorized x4.
__global__ __launch_bounds__(THREADS) void bias_relu(
    const float* __restrict__ in, const float* __restrict__ b,
    float* __restrict__ out, int total) {
  int i = blockIdx.x * THREADS + threadIdx.x;
  int idx = i * 4;
  if (idx >= total) return;
  float4 v = *(const float4*)(in + idx);
  int c = idx & 63;
  float4 bb = *(const float4*)(b + c);
  v.x = fmaxf(v.x + bb.x, 0.f);
  v.y = fmaxf(v.y + bb.y, 0.f);
  v.z = fmaxf(v.z + bb.z, 0.f);
  v.w = fmaxf(v.w + bb.w, 0.f);
  *(float4*)(out + idx) = v;
}

// Per-graph sum of A rows (batch is sorted; handle transitions generically).
// Each wave: 64-node chunk, lane = dim; run-length accumulate, atomic on change.
__global__ __launch_bounds__(THREADS) void graph_reduce(
    const float* __restrict__ A, const int* __restrict__ batch,
    float* __restrict__ B, float* __restrict__ counts, int N) {
  int lane = threadIdx.x & 63;
  int chunk = blockIdx.x * (THREADS >> 6) + (threadIdx.x >> 6);
  int n0 = chunk * 64;
  if (n0 >= N) return;
  int n1 = min(n0 + 64, N);
  int cur = batch[n0];
  float acc = 0.f, cnt = 0.f;
  for (int n = n0; n < n1; ++n) {
    int g = batch[n];
    if (g != cur) {
      unsafeAtomicAdd(&B[cur * 64 + lane], acc);
      if (lane == 0) unsafeAtomicAdd(&counts[cur], cnt);
      acc = 0.f; cnt = 0.f; cur = g;
    }
    acc += A[(size_t)n * 64 + lane];
    cnt += 1.f;
  }
  unsafeAtomicAdd(&B[cur * 64 + lane], acc);
  if (lane == 0) unsafeAtomicAdd(&counts[cur], cnt);
}

// graph_embed[g,j] = sum_k B[g,k]*W3[k,j] + counts[g]*b3[j]
__global__ __launch_bounds__(THREADS) void graph_out_k(
    const float* __restrict__ B, const float* __restrict__ W3,
    const float* __restrict__ b3, const float* __restrict__ counts,
    float* __restrict__ out, int G) {
  int j = threadIdx.x & 63;
  int g = blockIdx.x * (THREADS >> 6) + (threadIdx.x >> 6);
  if (g >= G) return;
  float acc = 0.f;
#pragma unroll
  for (int k = 0; k < 64; ++k) acc += B[g * 64 + k] * W3[k * 64 + j];
  out[g * 64 + j] = acc + counts[g] * b3[j];
}

extern "C" void kernel_launch(void* const* d_in, const int* in_sizes, int n_in,
                              void* d_out, int out_size, void* d_ws, size_t ws_size,
                              hipStream_t stream) {
  const float* x     = (const float*)d_in[0];
  const int*   ei    = (const int*)d_in[1];
  const float* ew    = (const float*)d_in[2];
  const int*   batch = (const int*)d_in[3];
  const float* W1    = (const float*)d_in[4];
  const float* b1    = (const float*)d_in[5];
  const float* W2    = (const float*)d_in[6];
  const float* b2    = (const float*)d_in[7];
  const float* W3    = (const float*)d_in[8];
  const float* b3    = (const float*)d_in[9];

  const int N = in_sizes[0] / 128;          // 50000
  const int E = in_sizes[1] / 2;            // 1600000
  const int G = (out_size - N * 64) / 64;   // 64
  const int* src = ei;
  const int* tgt = ei + E;

  float* out_embed = (float*)d_out;                     // [N,64]
  float* out_graph = (float*)d_out + (size_t)N * 64;    // [G,64]

  char* ws = (char*)d_ws;
  float* h      = (float*)ws;                                 // [N,64]
  float* agg    = (float*)(ws + (size_t)N * 64 * 4);          // [N,64]
  float* B      = (float*)(ws + (size_t)N * 64 * 8);          // [G,64]
  float* counts = B + (size_t)G * 64;                         // [G]

  hipMemsetAsync(agg, 0, (size_t)N * 64 * 4, stream);
  hipMemsetAsync(B, 0, (size_t)(G * 64 + G) * 4, stream);

  // h_pre = x @ W1
  gemm64<128, false><<<(N + 3) / 4, THREADS, 0, stream>>>(x, W1, nullptr, h, N);

  const int sblocks = 2048;
  const int nwaves = sblocks * (THREADS / 64);

  // agg1 = segsum(h_pre[src]*w, tgt)
  scatter_edges<<<sblocks, THREADS, 0, stream>>>(h, src, tgt, ew, agg, E, nwaves);

  // h1 = relu(agg1 + b1)  (into h)
  bias_relu<<<(N * 64 / 4 + THREADS - 1) / THREADS, THREADS, 0, stream>>>(agg, b1, h, N * 64);

  // A = segsum(h1[src]*w, tgt)  (reuse agg)
  hipMemsetAsync(agg, 0, (size_t)N * 64 * 4, stream);
  scatter_edges<<<sblocks, THREADS, 0, stream>>>(h, src, tgt, ew, agg, E, nwaves);

  // embed = A @ W2 + b2
  gemm64<64, true><<<(N + 3) / 4, THREADS, 0, stream>>>(agg, W2, b2, out_embed, N);

  // B[g] = sum_{i in g} A[i]; counts[g] = n_g
  int chunks = (N + 63) / 64;
  graph_reduce<<<(chunks + 3) / 4, THREADS, 0, stream>>>(agg, batch, B, counts, N);

  // graph_embed = B @ W3 + counts*b3
  graph_out_k<<<(G + 3) / 4, THREADS, 0, stream>>>(B, W3, b3, counts, out_graph, G);
}

// Round 2
// 371.450 us; speedup vs baseline: 2.3714x; 2.3714x over previous
//
#include <hip/hip_runtime.h>

// ---------------------------------------------------------------------------
// GCN: 3-layer, N=50000 nodes (128 feats), E=1.6M edges, 64 graphs.
//
// Algebra: segsum((h@W)[src]*w, tgt) == segsum(h[src]*w, tgt) @ W
//  => layers 2 and 3 share ONE aggregation pass A = segsum(h1[src]*w, tgt).
//
// Round 2 restructure: atomic scatter (400 MB HBM write-through per pass)
// replaced by CSR-by-target + gather (write once per node, 12.8 MB).
// CSR is PADDED (capacity PAD per node) so no prefix-sum is needed:
//   slot = atomicAdd(cnt[t],1) gives position AND final degree in one pass.
// In-degree ~ Poisson(32); P(deg>=72) ~ 1e-12/node -> PAD=80 is safe.
//
// Pipeline:
//   build_csr                      (1.6M int atomics on 200 KB - cheap)
//   h_pre = x @ W1                 (tiled GEMM K=128)
//   h1    = relu(gather(h_pre)+b1) (edge gather pass 1, fused epilogue)
//   A     = gather(h1)             (edge gather pass 2)
//   embed = A @ W2 + b2            (tiled GEMM K=64)
//   B[g]  = sum_{i in g} A[i]      (run-length reduce over sorted batch)
//   g_emb = B @ W3 + counts*b3
// ---------------------------------------------------------------------------

#define THREADS 256

// -------------------- CSR build (counting sort, padded) --------------------
__global__ __launch_bounds__(THREADS) void build_csr(
    const int* __restrict__ src, const int* __restrict__ tgt,
    const float* __restrict__ ew, int* __restrict__ cnt,
    int2* __restrict__ csr, int E, int PAD) {
  int e = blockIdx.x * THREADS + threadIdx.x;
  if (e >= E) return;
  int t = tgt[e];
  int slot = atomicAdd(&cnt[t], 1);
  if (slot < PAD)
    csr[(size_t)t * PAD + slot] = make_int2(src[e], __float_as_int(ew[e]));
}

// -------------------- gather pass: wave per node ---------------------------
// Lane = feature dim (64). Entries preloaded coalesced (lane j -> entry j),
// broadcast via v_readlane (scalar, uniform index) -> gather loads get the
// efficient saddr form. No atomics; one 256 B store per node.
template <bool RELU>
__global__ __launch_bounds__(THREADS) void gather_nodes(
    const float* __restrict__ h, const int2* __restrict__ csr,
    const int* __restrict__ deg, const float* __restrict__ b,
    float* __restrict__ out, int N, int PAD) {
  int lane = threadIdx.x & 63;
  int node = blockIdx.x * (THREADS >> 6) + (threadIdx.x >> 6);
  if (node >= N) return;
  int d = min(deg[node], PAD);
  const int2* ep = csr + (size_t)node * PAD;
  float acc0 = 0.f, acc1 = 0.f, acc2 = 0.f, acc3 = 0.f;
  int j0 = 0;
  while (j0 < d) {
    int take = min(64, d - j0);
    int2 ent = ep[j0 + min(lane, take - 1)];
    int sv = ent.x, wv = ent.y;
    int j = 0;
    for (; j + 4 <= take; j += 4) {
      int s0 = __builtin_amdgcn_readlane(sv, j + 0);
      int s1 = __builtin_amdgcn_readlane(sv, j + 1);
      int s2 = __builtin_amdgcn_readlane(sv, j + 2);
      int s3 = __builtin_amdgcn_readlane(sv, j + 3);
      float w0 = __int_as_float(__builtin_amdgcn_readlane(wv, j + 0));
      float w1 = __int_as_float(__builtin_amdgcn_readlane(wv, j + 1));
      float w2 = __int_as_float(__builtin_amdgcn_readlane(wv, j + 2));
      float w3 = __int_as_float(__builtin_amdgcn_readlane(wv, j + 3));
      float v0 = h[(size_t)s0 * 64 + lane];
      float v1 = h[(size_t)s1 * 64 + lane];
      float v2 = h[(size_t)s2 * 64 + lane];
      float v3 = h[(size_t)s3 * 64 + lane];
      acc0 = fmaf(v0, w0, acc0);
      acc1 = fmaf(v1, w1, acc1);
      acc2 = fmaf(v2, w2, acc2);
      acc3 = fmaf(v3, w3, acc3);
    }
    for (; j < take; ++j) {
      int s = __builtin_amdgcn_readlane(sv, j);
      float w = __int_as_float(__builtin_amdgcn_readlane(wv, j));
      acc0 = fmaf(h[(size_t)s * 64 + lane], w, acc0);
    }
    j0 += take;
  }
  float acc = (acc0 + acc1) + (acc2 + acc3);
  if (RELU) acc = fmaxf(acc + b[lane], 0.f);
  out[(size_t)node * 64 + lane] = acc;
}

// -------------------- tiled GEMM: C[M,64] = A[M,K] @ W[K,64] (+bias) -------
// Block = 64-row x 64-col tile, 256 threads, each thread 4x4 register tile.
template <int K, bool BIAS>
__global__ __launch_bounds__(THREADS) void gemm_tiled(
    const float* __restrict__ A, const float* __restrict__ W,
    const float* __restrict__ bias, float* __restrict__ C, int M) {
  __shared__ float Xs[64][K + 1];   // +1 pad: conflict-free k-column reads
  __shared__ float Ws[K][64];
  int tid = threadIdx.x;
  int r0 = blockIdx.x * 64;

  for (int i = tid * 4; i < K * 64; i += THREADS * 4)
    *(float4*)&Ws[0][i] = *(const float4*)(W + i);

  constexpr int KSH = (K == 128) ? 7 : 6;
  for (int i = tid * 4; i < 64 * K; i += THREADS * 4) {
    int row = i >> KSH, k = i & (K - 1);
    float4 v = make_float4(0.f, 0.f, 0.f, 0.f);
    if (r0 + row < M) v = *(const float4*)(A + (size_t)(r0 + row) * K + k);
    Xs[row][k] = v.x; Xs[row][k + 1] = v.y; Xs[row][k + 2] = v.z; Xs[row][k + 3] = v.w;
  }
  __syncthreads();

  int tx = tid & 15, ty = tid >> 4;   // col group, row group
  float acc[4][4] = {};
#pragma unroll 8
  for (int k = 0; k < K; ++k) {
    float4 w4 = *(const float4*)&Ws[k][tx * 4];
    float x0 = Xs[ty * 4 + 0][k];
    float x1 = Xs[ty * 4 + 1][k];
    float x2 = Xs[ty * 4 + 2][k];
    float x3 = Xs[ty * 4 + 3][k];
    acc[0][0] = fmaf(x0, w4.x, acc[0][0]); acc[0][1] = fmaf(x0, w4.y, acc[0][1]);
    acc[0][2] = fmaf(x0, w4.z, acc[0][2]); acc[0][3] = fmaf(x0, w4.w, acc[0][3]);
    acc[1][0] = fmaf(x1, w4.x, acc[1][0]); acc[1][1] = fmaf(x1, w4.y, acc[1][1]);
    acc[1][2] = fmaf(x1, w4.z, acc[1][2]); acc[1][3] = fmaf(x1, w4.w, acc[1][3]);
    acc[2][0] = fmaf(x2, w4.x, acc[2][0]); acc[2][1] = fmaf(x2, w4.y, acc[2][1]);
    acc[2][2] = fmaf(x2, w4.z, acc[2][2]); acc[2][3] = fmaf(x2, w4.w, acc[2][3]);
    acc[3][0] = fmaf(x3, w4.x, acc[3][0]); acc[3][1] = fmaf(x3, w4.y, acc[3][1]);
    acc[3][2] = fmaf(x3, w4.z, acc[3][2]); acc[3][3] = fmaf(x3, w4.w, acc[3][3]);
  }
#pragma unroll
  for (int i = 0; i < 4; ++i) {
    int r = r0 + ty * 4 + i;
    if (r >= M) continue;
    float4 o = make_float4(acc[i][0], acc[i][1], acc[i][2], acc[i][3]);
    if (BIAS) {
      float4 bb = *(const float4*)(bias + tx * 4);
      o.x += bb.x; o.y += bb.y; o.z += bb.z; o.w += bb.w;
    }
    *(float4*)(C + (size_t)r * 64 + tx * 4) = o;
  }
}

// -------------------- per-graph reduce (batch sorted) ----------------------
__global__ __launch_bounds__(THREADS) void graph_reduce(
    const float* __restrict__ A, const int* __restrict__ batch,
    float* __restrict__ B, float* __restrict__ counts, int N) {
  int lane = threadIdx.x & 63;
  int chunk = blockIdx.x * (THREADS >> 6) + (threadIdx.x >> 6);
  int n0 = chunk * 64;
  if (n0 >= N) return;
  int n1 = min(n0 + 64, N);
  int cur = batch[n0];
  float acc = 0.f, cnt = 0.f;
  for (int n = n0; n < n1; ++n) {
    int g = batch[n];
    if (g != cur) {
      unsafeAtomicAdd(&B[cur * 64 + lane], acc);
      if (lane == 0) unsafeAtomicAdd(&counts[cur], cnt);
      acc = 0.f; cnt = 0.f; cur = g;
    }
    acc += A[(size_t)n * 64 + lane];
    cnt += 1.f;
  }
  unsafeAtomicAdd(&B[cur * 64 + lane], acc);
  if (lane == 0) unsafeAtomicAdd(&counts[cur], cnt);
}

// graph_embed[g,j] = sum_k B[g,k]*W3[k,j] + counts[g]*b3[j]
__global__ __launch_bounds__(THREADS) void graph_out_k(
    const float* __restrict__ B, const float* __restrict__ W3,
    const float* __restrict__ b3, const float* __restrict__ counts,
    float* __restrict__ out, int G) {
  int j = threadIdx.x & 63;
  int g = blockIdx.x * (THREADS >> 6) + (threadIdx.x >> 6);
  if (g >= G) return;
  float acc = 0.f;
#pragma unroll
  for (int k = 0; k < 64; ++k) acc += B[g * 64 + k] * W3[k * 64 + j];
  out[g * 64 + j] = acc + counts[g] * b3[j];
}

extern "C" void kernel_launch(void* const* d_in, const int* in_sizes, int n_in,
                              void* d_out, int out_size, void* d_ws, size_t ws_size,
                              hipStream_t stream) {
  const float* x     = (const float*)d_in[0];
  const int*   ei    = (const int*)d_in[1];
  const float* ew    = (const float*)d_in[2];
  const int*   batch = (const int*)d_in[3];
  const float* W1    = (const float*)d_in[4];
  const float* b1    = (const float*)d_in[5];
  const float* W2    = (const float*)d_in[6];
  const float* b2    = (const float*)d_in[7];
  const float* W3    = (const float*)d_in[8];
  const float* b3    = (const float*)d_in[9];

  const int N = in_sizes[0] / 128;          // 50000
  const int E = in_sizes[1] / 2;            // 1600000
  const int G = (out_size - N * 64) / 64;   // 64
  const int* src = ei;
  const int* tgt = ei + E;

  float* out_embed = (float*)d_out;
  float* out_graph = (float*)d_out + (size_t)N * 64;

  char* ws = (char*)d_ws;
  float* buf0   = (float*)ws;                                  // [N,64] h_pre, later A
  float* buf1   = buf0 + (size_t)N * 64;                       // [N,64] h1
  int*   cnt    = (int*)(buf1 + (size_t)N * 64);               // [N]
  float* B      = (float*)(cnt + N);                           // [G,64]
  float* counts = B + (size_t)G * 64;                          // [G]
  size_t base   = (size_t)N * 64 * 8 + (size_t)N * 4 + (size_t)(G * 64 + G) * 4;
  size_t csr_off = (base + 255) & ~(size_t)255;
  int2*  csr    = (int2*)(ws + csr_off);
  int    PAD    = 80;
  if (ws_size > csr_off) {
    size_t cap = (ws_size - csr_off) / ((size_t)N * 8);
    if (cap < (size_t)PAD) PAD = (int)cap;
  }

  hipMemsetAsync(cnt, 0, (size_t)N * 4, stream);
  hipMemsetAsync(B, 0, (size_t)(G * 64 + G) * 4, stream);

  // CSR by target (padded, no prefix sum)
  build_csr<<<(E + THREADS - 1) / THREADS, THREADS, 0, stream>>>(
      src, tgt, ew, cnt, csr, E, PAD);

  // h_pre = x @ W1
  gemm_tiled<128, false><<<(N + 63) / 64, THREADS, 0, stream>>>(x, W1, nullptr, buf0, N);

  const int gblocks = (N + 3) / 4;
  // h1 = relu(gather(h_pre) + b1)
  gather_nodes<true><<<gblocks, THREADS, 0, stream>>>(buf0, csr, cnt, b1, buf1, N, PAD);
  // A = gather(h1)
  gather_nodes<false><<<gblocks, THREADS, 0, stream>>>(buf1, csr, cnt, nullptr, buf0, N, PAD);

  // embed = A @ W2 + b2
  gemm_tiled<64, true><<<(N + 63) / 64, THREADS, 0, stream>>>(buf0, W2, b2, out_embed, N);

  // B[g] = sum_{i in g} A[i]
  int chunks = (N + 63) / 64;
  graph_reduce<<<(chunks + 3) / 4, THREADS, 0, stream>>>(buf0, batch, B, counts, N);

  // graph_embed = B @ W3 + counts*b3
  graph_out_k<<<(G + 3) / 4, THREADS, 0, stream>>>(B, W3, b3, counts, out_graph, G);
}